// Round 1
// baseline (162.314 us; speedup 1.0000x reference)
//
#include <hip/hip_runtime.h>

#define NT 16384      // tokens = 4*4096
#define D  2048
#define E  64
#define BM 64
#define BK 64
#define XT_STRIDE 68  // pad: multiple of 4 floats (16B-aligned b128), breaks bank stride
#define LS_STRIDE 65

__global__ __launch_bounds__(256) void router_main(const float* __restrict__ x,
                                                   const float* __restrict__ W,
                                                   const float* __restrict__ b,
                                                   float* __restrict__ out,
                                                   float* __restrict__ ws) {
    __shared__ float Xt[BK * XT_STRIDE];   // transposed x tile [k][token]
    __shared__ float Wsh[BK * E];          // [k][expert]
    __shared__ float cnt[E];

    const int tid = threadIdx.x;
    const int tx  = tid & 15;      // expert group
    const int ty  = tid >> 4;      // token group 0..15
    const int c0  = tx * 4;        // first expert col of this thread
    const int r0  = (ty & 3) * 4 + (ty >> 2) * 16; // spread? no -- keep simple:
    // NOTE: simple mapping: r0 = ty*4 covers tokens 0..63 across ty=0..15
    const int row0 = ty * 4;
    const int t0  = blockIdx.x * BM;

    float acc[4][4] = {};

    const int srow = tid >> 4;        // 0..15 staging row
    const int scol = (tid & 15) * 4;  // 0..60 staging col (floats)

    for (int kb = 0; kb < D; kb += BK) {
        // ---- stage W tile [BK][E], row-major, coalesced ----
        #pragma unroll
        for (int p = 0; p < 4; ++p) {
            const int kr = srow + p * 16;
            const float4 w4 = *(const float4*)&W[(size_t)(kb + kr) * E + scol];
            *(float4*)&Wsh[kr * E + scol] = w4;
        }
        // ---- stage x tile transposed: Xt[k][token] ----
        #pragma unroll
        for (int p = 0; p < 4; ++p) {
            const int tr = srow + p * 16;  // token within tile
            const float4 v = *(const float4*)&x[(size_t)(t0 + tr) * D + kb + scol];
            Xt[(scol + 0) * XT_STRIDE + tr] = v.x;
            Xt[(scol + 1) * XT_STRIDE + tr] = v.y;
            Xt[(scol + 2) * XT_STRIDE + tr] = v.z;
            Xt[(scol + 3) * XT_STRIDE + tr] = v.w;
        }
        __syncthreads();

        // ---- inner product: per-tile sub-accumulator (better fp32 accuracy) ----
        float tacc[4][4] = {};
        #pragma unroll 8
        for (int kk = 0; kk < BK; ++kk) {
            const float4 xv = *(const float4*)&Xt[kk * XT_STRIDE + row0];
            const float4 wv = *(const float4*)&Wsh[kk * E + c0];
            const float xs[4] = {xv.x, xv.y, xv.z, xv.w};
            const float wsv[4] = {wv.x, wv.y, wv.z, wv.w};
            #pragma unroll
            for (int i = 0; i < 4; ++i)
                #pragma unroll
                for (int j = 0; j < 4; ++j)
                    tacc[i][j] = fmaf(xs[i], wsv[j], tacc[i][j]);
        }
        #pragma unroll
        for (int i = 0; i < 4; ++i)
            #pragma unroll
            for (int j = 0; j < 4; ++j)
                acc[i][j] += tacc[i][j];
        __syncthreads();
    }

    // ---- epilogue: logits -> LDS (reuse Xt as Ls[64][65]) ----
    float* Ls = Xt;
    float bv[4];
    #pragma unroll
    for (int j = 0; j < 4; ++j) bv[j] = b[c0 + j];

    if (tid < E) cnt[tid] = 0.0f;

    #pragma unroll
    for (int i = 0; i < 4; ++i)
        #pragma unroll
        for (int j = 0; j < 4; ++j)
            Ls[(row0 + i) * LS_STRIDE + c0 + j] = acc[i][j] + bv[j];
    __syncthreads();

    if (tid < BM) {
        const int t = tid;
        float* row = &Ls[t * LS_STRIDE];
        // pass 1: max
        float mx = -3.4e38f;
        #pragma unroll 8
        for (int e = 0; e < E; ++e) mx = fmaxf(mx, row[e]);
        // pass 2: sum of exp + top-2 (strict >, earlier index wins ties)
        float s = 0.0f;
        float v1 = -3.4e38f, v2 = -3.4e38f;
        int i1 = 0, i2 = 0;
        for (int e = 0; e < E; ++e) {
            const float l = row[e];
            s += expf(l - mx);
            if (l > v1) { v2 = v1; i2 = i1; v1 = l; i1 = e; }
            else if (l > v2) { v2 = l; i2 = e; }
        }
        const float inv_s = 1.0f / s;
        const float p1 = expf(v1 - mx) * inv_s;
        const float p2 = expf(v2 - mx) * inv_s;
        const int tg = t0 + t;
        // outputs: indices chunk [0, 32768), scores chunk [32768, 65536)
        out[tg * 2 + 0] = (float)i1;
        out[tg * 2 + 1] = (float)i2;
        out[NT * 2 + tg * 2 + 0] = p1;
        out[NT * 2 + tg * 2 + 1] = p2;
        // pass 3: write normalized probs back
        for (int e = 0; e < E; ++e) row[e] = expf(row[e] - mx) * inv_s;
        // dispatch counts
        atomicAdd(&cnt[i1], 1.0f);
        atomicAdd(&cnt[i2], 1.0f);
    }
    __syncthreads();

    if (tid < E) {
        const int e = tid;
        float colsum = 0.0f;
        #pragma unroll 8
        for (int t = 0; t < BM; ++t) colsum += Ls[t * LS_STRIDE + e];
        atomicAdd(&ws[e], colsum);        // sum of probs per expert
        atomicAdd(&ws[E + e], cnt[e]);    // dispatch counts per expert
    }
}

__global__ void router_aux(const float* __restrict__ ws, float* __restrict__ out) {
    const int e = threadIdx.x;
    float v = ws[e] * ws[E + e] * (1.0f / NT) * (1.0f / NT);
    #pragma unroll
    for (int off = 32; off > 0; off >>= 1) v += __shfl_down(v, off);
    if (e == 0) out[NT * 2 * 2] = (float)E * v;
}

extern "C" void kernel_launch(void* const* d_in, const int* in_sizes, int n_in,
                              void* d_out, int out_size, void* d_ws, size_t ws_size,
                              hipStream_t stream) {
    const float* x = (const float*)d_in[0];
    const float* W = (const float*)d_in[1];
    const float* b = (const float*)d_in[2];
    float* out = (float*)d_out;
    float* ws  = (float*)d_ws;

    hipMemsetAsync(d_ws, 0, 2 * E * sizeof(float), stream);
    router_main<<<dim3(NT / BM), dim3(256), 0, stream>>>(x, W, b, out, ws);
    router_aux<<<dim3(1), dim3(E), 0, stream>>>(ws, out);
}

// Round 2
// 95.072 us; speedup vs baseline: 1.7073x; 1.7073x over previous
//
#include <hip/hip_runtime.h>

#define NT 16384      // tokens = 4*4096
#define D  2048
#define E  64
#define BM 64
#define BK 32
#define NG 4              // K-groups per block
#define KCH (D / NG)      // 512 K per group
#define NTILES (KCH / BK) // 16

// smem layout (floats):
//   group g pane: [g*4096, g*4096+2048) = Xt[32][64] (swizzled), [g*4096+2048, g*4096+4096) = Wsh[32][64]
//   after compute: group g partial logits at [g*4096 + t*64 + e]
//   after reduce : combined logits Ls[t*65+e] in [0,4160); cnt[64] at [8192,8256)
__global__ __launch_bounds__(1024) void router_main(const float* __restrict__ x,
                                                    const float* __restrict__ W,
                                                    const float* __restrict__ bias,
                                                    float* __restrict__ out,
                                                    float* __restrict__ ws) {
    __shared__ float smem[16384];  // 64 KB

    const int tid = threadIdx.x;
    const int g   = tid >> 8;      // K-group 0..3
    const int q   = tid & 255;     // id within group
    float* Xt  = smem + g * 4096;
    float* Wsh = smem + g * 4096 + 2048;

    const int tx   = q & 15;       // expert group
    const int ty   = q >> 4;       // token group 0..15
    const int c0   = tx * 4;
    const int row0 = ty * 4;
    const int t0   = blockIdx.x * BM;

    float acc[4][4] = {};

    for (int kt = 0; kt < NTILES; ++kt) {
        const int kb = g * KCH + kt * BK;

        // ---- stage W tile [BK=32][64], linear, coalesced; 2 float4/thread ----
        #pragma unroll
        for (int l = 0; l < 2; ++l) {
            const int fid = q + l * 256;
            const int kr  = fid >> 4;         // 0..31
            const int c4  = (fid & 15) * 4;   // 0..60
            *(float4*)&Wsh[kr * 64 + c4] = *(const float4*)&W[(size_t)(kb + kr) * E + c4];
        }
        // ---- stage x tile transposed + XOR-swizzled: Xt[k][tok ^ ((k>>2)<<2)] ----
        #pragma unroll
        for (int l = 0; l < 2; ++l) {
            const int fid = q + l * 256;
            const int row = fid >> 3;         // token 0..63
            const int c4  = fid & 7;          // k-quad 0..7
            const float4 v = *(const float4*)&x[(size_t)(t0 + row) * D + kb + c4 * 4];
            const int swtok = row ^ (c4 << 2);
            Xt[(c4 * 4 + 0) * 64 + swtok] = v.x;
            Xt[(c4 * 4 + 1) * 64 + swtok] = v.y;
            Xt[(c4 * 4 + 2) * 64 + swtok] = v.z;
            Xt[(c4 * 4 + 3) * 64 + swtok] = v.w;
        }
        __syncthreads();

        // ---- inner product, per-tile sub-accumulator ----
        float tacc[4][4] = {};
        #pragma unroll 8
        for (int kk = 0; kk < BK; ++kk) {
            const float4 xv = *(const float4*)&Xt[kk * 64 + (row0 ^ (((kk >> 2) & 7) << 2))];
            const float4 wv = *(const float4*)&Wsh[kk * 64 + c0];
            const float xs[4]  = {xv.x, xv.y, xv.z, xv.w};
            const float wsv[4] = {wv.x, wv.y, wv.z, wv.w};
            #pragma unroll
            for (int i = 0; i < 4; ++i)
                #pragma unroll
                for (int j = 0; j < 4; ++j)
                    tacc[i][j] = fmaf(xs[i], wsv[j], tacc[i][j]);
        }
        #pragma unroll
        for (int i = 0; i < 4; ++i)
            #pragma unroll
            for (int j = 0; j < 4; ++j)
                acc[i][j] += tacc[i][j];
        __syncthreads();
    }

    // ---- each group writes its partial logits into its own pane (stride 64) ----
    #pragma unroll
    for (int i = 0; i < 4; ++i) {
        float4 v = {acc[i][0], acc[i][1], acc[i][2], acc[i][3]};
        *(float4*)&smem[g * 4096 + (row0 + i) * 64 + c0] = v;
    }
    __syncthreads();

    // ---- cross-group reduce: each of 1024 threads sums 4 slots ----
    float red[4];
    #pragma unroll
    for (int r = 0; r < 4; ++r) {
        const int slot = tid + r * 1024;
        red[r] = smem[slot] + smem[4096 + slot] + smem[8192 + slot] + smem[12288 + slot]
               + bias[slot & 63];
    }
    __syncthreads();
    #pragma unroll
    for (int r = 0; r < 4; ++r) {
        const int slot = tid + r * 1024;
        smem[(slot >> 6) * 65 + (slot & 63)] = red[r];  // Ls stride 65, [0,4160)
    }
    if (tid < E) smem[8192 + tid] = 0.0f;               // cnt
    __syncthreads();

    float* Ls  = smem;
    float* cnt = smem + 8192;

    if (tid < BM) {
        const int t = tid;
        float* row = &Ls[t * 65];
        float mx = -3.4e38f;
        #pragma unroll 8
        for (int e = 0; e < E; ++e) mx = fmaxf(mx, row[e]);
        float s = 0.0f;
        float v1 = -3.4e38f, v2 = -3.4e38f;
        int i1 = 0, i2 = 0;
        for (int e = 0; e < E; ++e) {
            const float l = row[e];
            s += expf(l - mx);
            if (l > v1) { v2 = v1; i2 = i1; v1 = l; i1 = e; }
            else if (l > v2) { v2 = l; i2 = e; }
        }
        const float inv_s = 1.0f / s;
        const float p1 = expf(v1 - mx) * inv_s;
        const float p2 = expf(v2 - mx) * inv_s;
        const int tg = t0 + t;
        out[tg * 2 + 0] = (float)i1;
        out[tg * 2 + 1] = (float)i2;
        out[NT * 2 + tg * 2 + 0] = p1;
        out[NT * 2 + tg * 2 + 1] = p2;
        for (int e = 0; e < E; ++e) row[e] = expf(row[e] - mx) * inv_s;
        atomicAdd(&cnt[i1], 1.0f);
        atomicAdd(&cnt[i2], 1.0f);
    }
    __syncthreads();

    if (tid < E) {
        const int e = tid;
        float colsum = 0.0f;
        #pragma unroll 8
        for (int t = 0; t < BM; ++t) colsum += Ls[t * 65 + e];
        atomicAdd(&ws[e], colsum);
        atomicAdd(&ws[E + e], cnt[e]);
    }
}

__global__ void router_aux(const float* __restrict__ ws, float* __restrict__ out) {
    const int e = threadIdx.x;
    float v = ws[e] * ws[E + e] * (1.0f / NT) * (1.0f / NT);
    #pragma unroll
    for (int off = 32; off > 0; off >>= 1) v += __shfl_down(v, off);
    if (e == 0) out[NT * 2 * 2] = (float)E * v;
}

extern "C" void kernel_launch(void* const* d_in, const int* in_sizes, int n_in,
                              void* d_out, int out_size, void* d_ws, size_t ws_size,
                              hipStream_t stream) {
    const float* x = (const float*)d_in[0];
    const float* W = (const float*)d_in[1];
    const float* b = (const float*)d_in[2];
    float* out = (float*)d_out;
    float* ws  = (float*)d_ws;

    hipMemsetAsync(d_ws, 0, 2 * E * sizeof(float), stream);
    router_main<<<dim3(NT / BM), dim3(1024), 0, stream>>>(x, W, b, out, ws);
    router_aux<<<dim3(1), dim3(E), 0, stream>>>(ws, out);
}

// Round 3
// 74.702 us; speedup vs baseline: 2.1728x; 1.2727x over previous
//
#include <hip/hip_runtime.h>

#define NT 16384
#define D  2048
#define E  64
#define BM 64
#define BK 64
#define NTILES (D / BK)   // 32

typedef _Float16 half8 __attribute__((ext_vector_type(8)));
typedef float f32x4 __attribute__((ext_vector_type(4)));

// f16-unit index into a [64 rows][64 k] pane, XOR-swizzled for conflict-free b128
__device__ __forceinline__ int swz(int row, int k) {
    return (row << 6) + (k ^ ((row & 7) << 3));
}

__global__ __launch_bounds__(256) void router_main(const float* __restrict__ x,
                                                   const float* __restrict__ W,
                                                   const float* __restrict__ bias,
                                                   float* __restrict__ out,
                                                   float* __restrict__ ws) {
    // [buf][pane: 0=Xh 1=Xl 2=Wh 3=Wl][64*64]  = 64 KiB
    __shared__ _Float16 lds[2][4][64 * 64];
    __shared__ float psum[E];
    __shared__ float cnts[E];

    const int tid  = threadIdx.x;
    const int lane = tid & 63;
    const int w    = tid >> 6;     // wave 0..3
    const int g    = lane >> 4;    // 0..3
    const int c    = lane & 15;
    const int t0   = blockIdx.x * BM;

    if (tid < E) { psum[tid] = 0.f; cnts[tid] = 0.f; }

    // staging coords
    const int xrow0 = tid >> 3;          // 0..31  (chunk1 = +32)
    const int xc8   = tid & 7;           // k-octet 0..7
    const int wk    = tid >> 4;          // 0..15  (+16p)
    const int we0   = (tid & 15) << 2;   // expert base 0..60

    float xa[16], wa[16], xb[16], wb[16];

    auto LOADX = [&](float* xr, int kb) {
        const float* p0 = &x[(size_t)(t0 + xrow0) * D + kb + xc8 * 8];
        const float* p1 = &x[(size_t)(t0 + xrow0 + 32) * D + kb + xc8 * 8];
        *(float4*)&xr[0]  = *(const float4*)p0;
        *(float4*)&xr[4]  = *(const float4*)(p0 + 4);
        *(float4*)&xr[8]  = *(const float4*)p1;
        *(float4*)&xr[12] = *(const float4*)(p1 + 4);
    };
    auto LOADW = [&](float* wr, int kb) {
        #pragma unroll
        for (int p = 0; p < 4; ++p)
            *(float4*)&wr[p * 4] = *(const float4*)&W[(size_t)(kb + wk + 16 * p) * E + we0];
    };
    auto STOREX = [&](const float* xr, _Float16* Xh, _Float16* Xl) {
        #pragma unroll
        for (int ch = 0; ch < 2; ++ch) {
            half8 h, l;
            #pragma unroll
            for (int j = 0; j < 8; ++j) {
                float v  = xr[ch * 8 + j];
                float hf = (float)(_Float16)v;
                h[j] = (_Float16)hf;
                l[j] = (_Float16)((v - hf) * 2048.f);
            }
            const int row = xrow0 + ch * 32;
            *(half8*)&Xh[swz(row, xc8 * 8)] = h;
            *(half8*)&Xl[swz(row, xc8 * 8)] = l;
        }
    };
    auto STOREW = [&](const float* wr, _Float16* Wh, _Float16* Wl) {
        #pragma unroll
        for (int p = 0; p < 4; ++p)
            #pragma unroll
            for (int i = 0; i < 4; ++i) {
                float v  = wr[p * 4 + i];
                float hf = (float)(_Float16)v;
                hf = (fabsf(hf) < 6.1035156e-5f) ? 0.f : hf;  // FTZ guard
                const int e = we0 + i, k = wk + 16 * p;
                Wh[swz(e, k)] = (_Float16)hf;
                Wl[swz(e, k)] = (_Float16)((v - hf) * 2048.f);
            }
    };

    f32x4 am[4] = {{0.f,0.f,0.f,0.f},{0.f,0.f,0.f,0.f},{0.f,0.f,0.f,0.f},{0.f,0.f,0.f,0.f}};
    f32x4 ac[4] = {{0.f,0.f,0.f,0.f},{0.f,0.f,0.f,0.f},{0.f,0.f,0.f,0.f},{0.f,0.f,0.f,0.f}};

    auto COMPUTE = [&](const _Float16* Xh, const _Float16* Xl,
                       const _Float16* Wh, const _Float16* Wl) {
        const int trow = w * 16 + c;
        #pragma unroll
        for (int kf = 0; kf < 2; ++kf) {
            const int kb8 = kf * 32 + g * 8;
            half8 bh = *(const half8*)&Xh[swz(trow, kb8)];
            half8 bl = *(const half8*)&Xl[swz(trow, kb8)];
            #pragma unroll
            for (int m = 0; m < 4; ++m) {
                half8 ah = *(const half8*)&Wh[swz(m * 16 + c, kb8)];
                half8 al = *(const half8*)&Wl[swz(m * 16 + c, kb8)];
                am[m] = __builtin_amdgcn_mfma_f32_16x16x32_f16(ah, bh, am[m], 0, 0, 0);
                ac[m] = __builtin_amdgcn_mfma_f32_16x16x32_f16(ah, bl, ac[m], 0, 0, 0);
                ac[m] = __builtin_amdgcn_mfma_f32_16x16x32_f16(al, bh, ac[m], 0, 0, 0);
            }
        }
    };

    LOADX(xa, 0); LOADW(wa, 0);
    #pragma unroll 1
    for (int t = 0; t < NTILES; t += 2) {
        if (t + 1 < NTILES) { LOADX(xb, (t + 1) * BK); LOADW(wb, (t + 1) * BK); }
        STOREX(xa, lds[0][0], lds[0][1]); STOREW(wa, lds[0][2], lds[0][3]);
        __syncthreads();
        COMPUTE(lds[0][0], lds[0][1], lds[0][2], lds[0][3]);
        if (t + 2 < NTILES) { LOADX(xa, (t + 2) * BK); LOADW(wa, (t + 2) * BK); }
        STOREX(xb, lds[1][0], lds[1][1]); STOREW(wb, lds[1][2], lds[1][3]);
        __syncthreads();
        COMPUTE(lds[1][0], lds[1][1], lds[1][2], lds[1][3]);
    }

    // ---------------- epilogue: all in-register ----------------
    // lane holds C[e][token]: e = m*16 + g*4 + r, token = t0 + w*16 + c
    const int tg = t0 + w * 16 + c;
    float lg[4][4];
    #pragma unroll
    for (int m = 0; m < 4; ++m)
        #pragma unroll
        for (int r = 0; r < 4; ++r)
            lg[m][r] = am[m][r] + ac[m][r] * (1.f / 2048.f) + bias[m * 16 + g * 4 + r];

    // local top-2 over this lane's 16 experts
    float v1 = -3.4e38f, v2 = -3.4e38f; int i1 = 0, i2 = 0;
    #pragma unroll
    for (int m = 0; m < 4; ++m)
        #pragma unroll
        for (int r = 0; r < 4; ++r) {
            const float v = lg[m][r];
            const int   e = m * 16 + g * 4 + r;
            if (v > v1) { v2 = v1; i2 = i1; v1 = v; i1 = e; }
            else if (v > v2) { v2 = v; i2 = e; }
        }
    // merge across the 4 lanes holding this token (xor 16, 32)
    #pragma unroll
    for (int mask = 16; mask <= 32; mask <<= 1) {
        const float ov1 = __shfl_xor(v1, mask, 64); const int oi1 = __shfl_xor(i1, mask, 64);
        const float ov2 = __shfl_xor(v2, mask, 64); const int oi2 = __shfl_xor(i2, mask, 64);
        const bool oTop = (ov1 > v1) || (ov1 == v1 && oi1 < i1);
        if (oTop) {
            const bool k2 = (v1 > ov2) || (v1 == ov2 && i1 < oi2);
            v2 = k2 ? v1 : ov2; i2 = k2 ? i1 : oi2;
            v1 = ov1; i1 = oi1;
        } else {
            const bool k2 = (ov1 > v2) || (ov1 == v2 && oi1 < i2);
            v2 = k2 ? ov1 : v2; i2 = k2 ? oi1 : i2;
        }
    }

    // softmax with mx = v1 (true max)
    float s = 0.f;
    #pragma unroll
    for (int m = 0; m < 4; ++m)
        #pragma unroll
        for (int r = 0; r < 4; ++r) {
            lg[m][r] = expf(lg[m][r] - v1);
            s += lg[m][r];
        }
    s += __shfl_xor(s, 16, 64);
    s += __shfl_xor(s, 32, 64);
    const float inv = 1.f / s;

    // normalized probs; then reduce over the 16 tokens of this wave (lanes c=0..15)
    #pragma unroll
    for (int m = 0; m < 4; ++m)
        #pragma unroll
        for (int r = 0; r < 4; ++r) {
            lg[m][r] *= inv;
            #pragma unroll
            for (int mask = 1; mask <= 8; mask <<= 1)
                lg[m][r] += __shfl_xor(lg[m][r], mask, 64);
        }
    if (c == 0) {
        #pragma unroll
        for (int m = 0; m < 4; ++m)
            #pragma unroll
            for (int r = 0; r < 4; ++r)
                atomicAdd(&psum[m * 16 + g * 4 + r], lg[m][r]);
    }
    if (g == 0) {  // one leader lane per token
        const float p2 = expf(v2 - v1) * inv;
        out[tg * 2 + 0] = (float)i1;
        out[tg * 2 + 1] = (float)i2;
        out[2 * NT + tg * 2 + 0] = inv;   // p1 = exp(0)/s
        out[2 * NT + tg * 2 + 1] = p2;
        atomicAdd(&cnts[i1], 1.f);
        atomicAdd(&cnts[i2], 1.f);
    }
    __syncthreads();
    if (tid < E) {
        atomicAdd(&ws[tid], psum[tid]);
        atomicAdd(&ws[E + tid], cnts[tid]);
    }
}

__global__ void router_aux(const float* __restrict__ ws, float* __restrict__ out) {
    const int e = threadIdx.x;
    float v = ws[e] * ws[E + e] * (1.0f / NT) * (1.0f / NT);
    #pragma unroll
    for (int off = 32; off > 0; off >>= 1) v += __shfl_down(v, off);
    if (e == 0) out[NT * 2 * 2] = (float)E * v;
}

extern "C" void kernel_launch(void* const* d_in, const int* in_sizes, int n_in,
                              void* d_out, int out_size, void* d_ws, size_t ws_size,
                              hipStream_t stream) {
    const float* x = (const float*)d_in[0];
    const float* W = (const float*)d_in[1];
    const float* b = (const float*)d_in[2];
    float* out = (float*)d_out;
    float* ws  = (float*)d_ws;

    hipMemsetAsync(d_ws, 0, 2 * E * sizeof(float), stream);
    router_main<<<dim3(NT / BM), dim3(256), 0, stream>>>(x, W, b, out, ws);
    router_aux<<<dim3(1), dim3(E), 0, stream>>>(ws, out);
}